// Round 1
// baseline (313.992 us; speedup 1.0000x reference)
//
#include <hip/hip_runtime.h>

typedef unsigned short u16;
typedef short short8 __attribute__((ext_vector_type(8)));
typedef float f32x4 __attribute__((ext_vector_type(4)));

#define EPS 1e-3f

static __device__ __forceinline__ u16 f2bf(float f) {
    unsigned int u = __float_as_uint(f);
    u += 0x7fffu + ((u >> 16) & 1u);   // round-to-nearest-even
    return (u16)(u >> 16);
}

// ---------------------------------------------------------------------------
// prep: fp32 weights -> bf16 transposed [N][K]; concat qkv weights + biases
// ---------------------------------------------------------------------------
__global__ void prep_kernel(const float* __restrict__ wq, const float* __restrict__ wk,
                            const float* __restrict__ wv, const float* __restrict__ wo,
                            const float* __restrict__ w1, const float* __restrict__ w2,
                            const float* __restrict__ bq, const float* __restrict__ bk,
                            const float* __restrict__ bv,
                            u16* __restrict__ wqkvT, u16* __restrict__ woT,
                            u16* __restrict__ w1T, u16* __restrict__ w2T,
                            float* __restrict__ bqkv) {
    int idx = blockIdx.x * 256 + threadIdx.x;
    if (idx < 196608) {                       // wqkvT [768][256]
        int n = idx >> 8, k = idx & 255;
        const float* w = (n < 256) ? wq : (n < 512 ? wk : wv);
        wqkvT[idx] = f2bf(w[k * 256 + (n & 255)]);
    } else if (idx < 262144) {                // woT [256][256]
        int i = idx - 196608; int n = i >> 8, k = i & 255;
        woT[i] = f2bf(wo[k * 256 + n]);
    } else if (idx < 524288) {                // w1T [1024][256]
        int i = idx - 262144; int n = i >> 8, k = i & 255;
        w1T[i] = f2bf(w1[k * 1024 + n]);
    } else if (idx < 786432) {                // w2T [256][1024]
        int i = idx - 524288; int n = i >> 10, k = i & 1023;
        w2T[i] = f2bf(w2[k * 256 + n]);
    } else if (idx < 787200) {                // bqkv [768]
        int i = idx - 786432;
        bqkv[i] = (i < 256) ? bq[i] : (i < 512 ? bk[i - 256] : bv[i - 512]);
    }
}

// ---------------------------------------------------------------------------
// bn1: h = bn(x) -> bf16, [8192][256]
// ---------------------------------------------------------------------------
__global__ void bn1_kernel(const float* __restrict__ x, const float* __restrict__ g,
                           const float* __restrict__ b, const float* __restrict__ m,
                           const float* __restrict__ v, u16* __restrict__ h) {
    int idx = blockIdx.x * 256 + threadIdx.x;     // one thread = 4 elems
    int base = idx * 4;
    int c = base & 255;
    float4 xv = *(const float4*)(x + base);
    float vals[4] = {xv.x, xv.y, xv.z, xv.w};
    u16 ov[4];
#pragma unroll
    for (int j = 0; j < 4; ++j) {
        float sc = g[c + j] * rsqrtf(v[c + j] + EPS);
        float sh = b[c + j] - m[c + j] * sc;
        ov[j] = f2bf(vals[j] * sc + sh);
    }
    ushort4 pk; pk.x = ov[0]; pk.y = ov[1]; pk.z = ov[2]; pk.w = ov[3];
    *(ushort4*)(h + base) = pk;
}

// ---------------------------------------------------------------------------
// GEMM: C[M,N] = A[M,K] (bf16) @ Bt[N,K]^T (bf16) with fused epilogues.
// 128x64 WG tile, BK=64, 4 waves; wave computes 32 rows x 64 cols.
// EPI 0: +bias            -> bf16 out
// EPI 1: +bias +resid     -> f32 out (x1)  AND  bn2 -> bf16 out (h2)
// EPI 2: gelu(exact)      -> bf16 out
// EPI 3: +resid           -> f32 out
// ---------------------------------------------------------------------------
template <int EPI>
__global__ __launch_bounds__(256) void gemm_bt(
        const u16* __restrict__ A, const u16* __restrict__ Bt,
        int M, int N, int K,
        const float* __restrict__ bias, const float* __restrict__ resid,
        float* __restrict__ out_f32, u16* __restrict__ out_bf,
        const float* __restrict__ bn_g, const float* __restrict__ bn_b,
        const float* __restrict__ bn_m, const float* __restrict__ bn_v) {
    __shared__ u16 lds_a[128][72];
    __shared__ u16 lds_b[64][72];
    const int t = threadIdx.x;
    const int wave = t >> 6, lane = t & 63;
    const int lane15 = lane & 15, quad = lane >> 4;
    const int m0 = blockIdx.x * 128;
    const int n0 = blockIdx.y * 64;

    f32x4 acc[2][4];
#pragma unroll
    for (int i = 0; i < 2; ++i)
#pragma unroll
        for (int j = 0; j < 4; ++j) acc[i][j] = (f32x4){0.f, 0.f, 0.f, 0.f};

    for (int k0 = 0; k0 < K; k0 += 64) {
        __syncthreads();
#pragma unroll
        for (int i = 0; i < 4; ++i) {            // A tile: 128x64
            int c = t + i * 256;
            int row = c >> 3, c8 = c & 7;
            uint4 val = *(const uint4*)(A + (size_t)(m0 + row) * K + k0 + c8 * 8);
            *(uint4*)(&lds_a[row][c8 * 8]) = val;
        }
#pragma unroll
        for (int i = 0; i < 2; ++i) {            // B tile: 64x64
            int c = t + i * 256;
            int row = c >> 3, c8 = c & 7;
            uint4 val = *(const uint4*)(Bt + (size_t)(n0 + row) * K + k0 + c8 * 8);
            *(uint4*)(&lds_b[row][c8 * 8]) = val;
        }
        __syncthreads();
#pragma unroll
        for (int kd = 0; kd < 2; ++kd) {
            short8 afr[2], bfr[4];
#pragma unroll
            for (int mt = 0; mt < 2; ++mt)
                afr[mt] = *(const short8*)(&lds_a[wave * 32 + mt * 16 + lane15][kd * 32 + quad * 8]);
#pragma unroll
            for (int nt = 0; nt < 4; ++nt)
                bfr[nt] = *(const short8*)(&lds_b[nt * 16 + lane15][kd * 32 + quad * 8]);
#pragma unroll
            for (int mt = 0; mt < 2; ++mt)
#pragma unroll
                for (int nt = 0; nt < 4; ++nt)
                    acc[mt][nt] = __builtin_amdgcn_mfma_f32_16x16x32_bf16(
                        afr[mt], bfr[nt], acc[mt][nt], 0, 0, 0);
        }
    }

#pragma unroll
    for (int mt = 0; mt < 2; ++mt)
#pragma unroll
        for (int nt = 0; nt < 4; ++nt)
#pragma unroll
            for (int r = 0; r < 4; ++r) {
                int row = m0 + wave * 32 + mt * 16 + quad * 4 + r;
                int col = n0 + nt * 16 + lane15;
                float val = acc[mt][nt][r];
                size_t oidx = (size_t)row * N + col;
                if (EPI == 0) {
                    out_bf[oidx] = f2bf(val + bias[col]);
                } else if (EPI == 1) {
                    val += bias[col] + resid[oidx];
                    out_f32[oidx] = val;
                    float sc = bn_g[col] * rsqrtf(bn_v[col] + EPS);
                    float sh = bn_b[col] - bn_m[col] * sc;
                    out_bf[oidx] = f2bf(val * sc + sh);
                } else if (EPI == 2) {
                    float gl = 0.5f * val * (1.f + erff(val * 0.70710678118654752f));
                    out_bf[oidx] = f2bf(gl);
                } else {
                    out_f32[oidx] = val + resid[oidx];
                }
            }
}

// ---------------------------------------------------------------------------
// Flash attention: qkv [8192][768] bf16 (q|k|v each 256 cols, head-major 64),
// one WG per (q-tile of 128 rows, b*h). Online softmax, ctx bf16 [8192][256].
// ---------------------------------------------------------------------------
__global__ __launch_bounds__(256) void attn_kernel(const u16* __restrict__ qkv,
                                                   u16* __restrict__ ctx) {
    __shared__ u16 lds_k[64][72];
    __shared__ u16 lds_vt[64][72];
    __shared__ u16 lds_p[128][72];
    const int t = threadIdx.x;
    const int wave = t >> 6, lane = t & 63;
    const int lane15 = lane & 15, quad = lane >> 4;
    const int qt = blockIdx.x;          // 0..15
    const int bh = blockIdx.y;          // 0..15
    const int bb = bh >> 2, hd = bh & 3;
    const size_t rowbase = (size_t)bb * 2048;

    // Q fragments stay in registers for the whole K loop
    short8 qf[2][2];
#pragma unroll
    for (int mt = 0; mt < 2; ++mt)
#pragma unroll
        for (int kd = 0; kd < 2; ++kd) {
            int row = qt * 128 + wave * 32 + mt * 16 + lane15;
            qf[mt][kd] = *(const short8*)(qkv + (rowbase + row) * 768 + hd * 64 + kd * 32 + quad * 8);
        }

    f32x4 o[2][4];
#pragma unroll
    for (int i = 0; i < 2; ++i)
#pragma unroll
        for (int j = 0; j < 4; ++j) o[i][j] = (f32x4){0.f, 0.f, 0.f, 0.f};
    float mst[2][4], lst[2][4];
#pragma unroll
    for (int i = 0; i < 2; ++i)
#pragma unroll
        for (int r = 0; r < 4; ++r) { mst[i][r] = -1e30f; lst[i][r] = 0.f; }

    for (int kt = 0; kt < 32; ++kt) {
        __syncthreads();
#pragma unroll
        for (int i = 0; i < 2; ++i) {        // stage K tile [64][64]
            int c = t + i * 256;
            int row = c >> 3, c8 = c & 7;
            uint4 val = *(const uint4*)(qkv + (rowbase + kt * 64 + row) * 768 + 256 + hd * 64 + c8 * 8);
            *(uint4*)(&lds_k[row][c8 * 8]) = val;
        }
#pragma unroll
        for (int i = 0; i < 2; ++i) {        // stage V transposed [d][s]
            int c = t + i * 256;
            int row = c >> 3, c8 = c & 7;
            short8 vv = *(const short8*)(qkv + (rowbase + kt * 64 + row) * 768 + 512 + hd * 64 + c8 * 8);
#pragma unroll
            for (int j = 0; j < 8; ++j) lds_vt[c8 * 8 + j][row] = (u16)vv[j];
        }
        __syncthreads();

        // scores S = Q K^T * 0.125
        f32x4 s[2][4];
#pragma unroll
        for (int i = 0; i < 2; ++i)
#pragma unroll
            for (int j = 0; j < 4; ++j) s[i][j] = (f32x4){0.f, 0.f, 0.f, 0.f};
#pragma unroll
        for (int kd = 0; kd < 2; ++kd) {
            short8 kf[4];
#pragma unroll
            for (int nt = 0; nt < 4; ++nt)
                kf[nt] = *(const short8*)(&lds_k[nt * 16 + lane15][kd * 32 + quad * 8]);
#pragma unroll
            for (int mt = 0; mt < 2; ++mt)
#pragma unroll
                for (int nt = 0; nt < 4; ++nt)
                    s[mt][nt] = __builtin_amdgcn_mfma_f32_16x16x32_bf16(
                        qf[mt][kd], kf[nt], s[mt][nt], 0, 0, 0);
        }

        // online softmax per row (row = quad*4+r within each 16-tile)
#pragma unroll
        for (int mt = 0; mt < 2; ++mt)
#pragma unroll
            for (int r = 0; r < 4; ++r) {
                float s0 = s[mt][0][r] * 0.125f;
                float s1 = s[mt][1][r] * 0.125f;
                float s2 = s[mt][2][r] * 0.125f;
                float s3 = s[mt][3][r] * 0.125f;
                float mx = fmaxf(fmaxf(s0, s1), fmaxf(s2, s3));
#pragma unroll
                for (int off = 8; off >= 1; off >>= 1)
                    mx = fmaxf(mx, __shfl_xor(mx, off, 16));
                float mnew = fmaxf(mst[mt][r], mx);
                float alpha = __expf(mst[mt][r] - mnew);
                float p0 = __expf(s0 - mnew);
                float p1 = __expf(s1 - mnew);
                float p2 = __expf(s2 - mnew);
                float p3 = __expf(s3 - mnew);
                float rs = p0 + p1 + p2 + p3;
#pragma unroll
                for (int off = 8; off >= 1; off >>= 1)
                    rs += __shfl_xor(rs, off, 16);
                lst[mt][r] = lst[mt][r] * alpha + rs;
                mst[mt][r] = mnew;
#pragma unroll
                for (int nt = 0; nt < 4; ++nt) o[mt][nt][r] *= alpha;
                int prow = wave * 32 + mt * 16 + quad * 4 + r;
                lds_p[prow][0 * 16 + lane15] = f2bf(p0);
                lds_p[prow][1 * 16 + lane15] = f2bf(p1);
                lds_p[prow][2 * 16 + lane15] = f2bf(p2);
                lds_p[prow][3 * 16 + lane15] = f2bf(p3);
            }

        // O += P @ V   (P read back in A-layout from per-wave LDS region)
#pragma unroll
        for (int kd = 0; kd < 2; ++kd) {
            short8 pf[2], vf[4];
#pragma unroll
            for (int mt = 0; mt < 2; ++mt)
                pf[mt] = *(const short8*)(&lds_p[wave * 32 + mt * 16 + lane15][kd * 32 + quad * 8]);
#pragma unroll
            for (int nt = 0; nt < 4; ++nt)
                vf[nt] = *(const short8*)(&lds_vt[nt * 16 + lane15][kd * 32 + quad * 8]);
#pragma unroll
            for (int mt = 0; mt < 2; ++mt)
#pragma unroll
                for (int nt = 0; nt < 4; ++nt)
                    o[mt][nt] = __builtin_amdgcn_mfma_f32_16x16x32_bf16(
                        pf[mt], vf[nt], o[mt][nt], 0, 0, 0);
        }
    }

    // epilogue: ctx = O / l
#pragma unroll
    for (int mt = 0; mt < 2; ++mt)
#pragma unroll
        for (int nt = 0; nt < 4; ++nt)
#pragma unroll
            for (int r = 0; r < 4; ++r) {
                int row = qt * 128 + wave * 32 + mt * 16 + quad * 4 + r;
                int col = hd * 64 + nt * 16 + lane15;
                ctx[(rowbase + row) * 256 + col] = f2bf(o[mt][nt][r] / lst[mt][r]);
            }
}

// ---------------------------------------------------------------------------
extern "C" void kernel_launch(void* const* d_in, const int* in_sizes, int n_in,
                              void* d_out, int out_size, void* d_ws, size_t ws_size,
                              hipStream_t stream) {
    (void)in_sizes; (void)n_in; (void)out_size; (void)ws_size;
    const float* x  = (const float*)d_in[0];
    const float* g1 = (const float*)d_in[1];
    const float* b1 = (const float*)d_in[2];
    const float* m1 = (const float*)d_in[3];
    const float* v1 = (const float*)d_in[4];
    const float* wq = (const float*)d_in[5];
    const float* bq = (const float*)d_in[6];
    const float* wk = (const float*)d_in[7];
    const float* bk = (const float*)d_in[8];
    const float* wv = (const float*)d_in[9];
    const float* bv = (const float*)d_in[10];
    const float* wo = (const float*)d_in[11];
    const float* bo = (const float*)d_in[12];
    const float* g2 = (const float*)d_in[13];
    const float* b2 = (const float*)d_in[14];
    const float* m2 = (const float*)d_in[15];
    const float* v2 = (const float*)d_in[16];
    const float* w1 = (const float*)d_in[17];
    const float* w2 = (const float*)d_in[18];

    char* ws = (char*)d_ws;
    u16*   h_buf = (u16*)(ws + 0);            // [8192][256] bf16
    u16*   qkv   = (u16*)(ws + 4194304);      // [8192][768] bf16
    u16*   ctx   = (u16*)(ws + 16777216);     // [8192][256] bf16
    float* x1    = (float*)(ws + 20971520);   // [8192][256] f32
    u16*   h2    = (u16*)(ws + 29360128);     // [8192][256] bf16
    u16*   gbuf  = (u16*)(ws + 33554432);     // [8192][1024] bf16
    u16*   wqkvT = (u16*)(ws + 50331648);     // [768][256] bf16
    u16*   woT   = (u16*)(ws + 50724864);     // [256][256] bf16
    u16*   w1T   = (u16*)(ws + 50855936);     // [1024][256] bf16
    u16*   w2T   = (u16*)(ws + 51380224);     // [256][1024] bf16
    float* bqkv  = (float*)(ws + 51904512);   // [768] f32
    float* out   = (float*)d_out;

    prep_kernel<<<3075, 256, 0, stream>>>(wq, wk, wv, wo, w1, w2, bq, bk, bv,
                                          wqkvT, woT, w1T, w2T, bqkv);
    bn1_kernel<<<2048, 256, 0, stream>>>(x, g1, b1, m1, v1, h_buf);
    gemm_bt<0><<<dim3(64, 12), 256, 0, stream>>>(h_buf, wqkvT, 8192, 768, 256,
                                                 bqkv, nullptr, nullptr, qkv,
                                                 nullptr, nullptr, nullptr, nullptr);
    attn_kernel<<<dim3(16, 16), 256, 0, stream>>>(qkv, ctx);
    gemm_bt<1><<<dim3(64, 4), 256, 0, stream>>>(ctx, woT, 8192, 256, 256,
                                                bo, x, x1, h2, g2, b2, m2, v2);
    gemm_bt<2><<<dim3(64, 16), 256, 0, stream>>>(h2, w1T, 8192, 1024, 256,
                                                 nullptr, nullptr, nullptr, gbuf,
                                                 nullptr, nullptr, nullptr, nullptr);
    gemm_bt<3><<<dim3(64, 4), 256, 0, stream>>>(gbuf, w2T, 8192, 256, 1024,
                                                nullptr, x1, out, nullptr,
                                                nullptr, nullptr, nullptr, nullptr);
}

// Round 2
// 288.891 us; speedup vs baseline: 1.0869x; 1.0869x over previous
//
#include <hip/hip_runtime.h>

typedef unsigned short u16;
typedef unsigned int u32;
typedef short short8 __attribute__((ext_vector_type(8)));
typedef float f32x4 __attribute__((ext_vector_type(4)));

#define EPS 1e-3f

static __device__ __forceinline__ u16 f2bf(float f) {
    u32 u = __float_as_uint(f);
    u += 0x7fffu + ((u >> 16) & 1u);   // round-to-nearest-even
    return (u16)(u >> 16);
}
// pack two floats to bf16 pair (round-half-up): low half = a, high half = b
static __device__ __forceinline__ u32 pack_bf2(float a, float b) {
    u32 ua = __float_as_uint(a) + 0x8000u;
    u32 ub = __float_as_uint(b) + 0x8000u;
    return __builtin_amdgcn_perm(ub, ua, 0x07060302u);
}

// ---------------------------------------------------------------------------
// prep: weights -> bf16 [N][K]; qk-concat; bn scale/shift precompute
// ---------------------------------------------------------------------------
__global__ void prep_kernel(const float* __restrict__ wq, const float* __restrict__ wk,
                            const float* __restrict__ wv, const float* __restrict__ wo,
                            const float* __restrict__ w1, const float* __restrict__ w2,
                            const float* __restrict__ bq, const float* __restrict__ bk,
                            const float* __restrict__ g1, const float* __restrict__ b1,
                            const float* __restrict__ m1, const float* __restrict__ v1,
                            const float* __restrict__ g2, const float* __restrict__ b2,
                            const float* __restrict__ m2, const float* __restrict__ v2,
                            u16* __restrict__ wqkT, u16* __restrict__ wvT,
                            u16* __restrict__ woT, u16* __restrict__ w1T,
                            u16* __restrict__ w2T, float* __restrict__ bqk,
                            float* __restrict__ bn1sc, float* __restrict__ bn1sh,
                            float* __restrict__ bn2sc, float* __restrict__ bn2sh) {
    int idx = blockIdx.x * 256 + threadIdx.x;
    if (idx < 131072) {                       // wqkT [512][256]
        int n = idx >> 8, k = idx & 255;
        float v = (n < 256) ? wq[k * 256 + n] : wk[k * 256 + (n - 256)];
        wqkT[idx] = f2bf(v);
    } else if (idx < 196608) {                // wvT [256][256]
        int i = idx - 131072; int n = i >> 8, k = i & 255;
        wvT[i] = f2bf(wv[k * 256 + n]);
    } else if (idx < 262144) {                // woT [256][256]
        int i = idx - 196608; int n = i >> 8, k = i & 255;
        woT[i] = f2bf(wo[k * 256 + n]);
    } else if (idx < 524288) {                // w1T [1024][256]
        int i = idx - 262144; int n = i >> 8, k = i & 255;
        w1T[i] = f2bf(w1[k * 1024 + n]);
    } else if (idx < 786432) {                // w2T [256][1024]
        int i = idx - 524288; int n = i >> 10, k = i & 1023;
        w2T[i] = f2bf(w2[k * 256 + n]);
    } else if (idx < 786944) {                // bqk [512]
        int i = idx - 786432;
        bqk[i] = (i < 256) ? bq[i] : bk[i - 256];
    } else if (idx < 787200) {                // bn1 sc/sh
        int i = idx - 786944;
        float sc = g1[i] * rsqrtf(v1[i] + EPS);
        bn1sc[i] = sc; bn1sh[i] = b1[i] - m1[i] * sc;
    } else if (idx < 787456) {                // bn2 sc/sh
        int i = idx - 787200;
        float sc = g2[i] * rsqrtf(v2[i] + EPS);
        bn2sc[i] = sc; bn2sh[i] = b2[i] - m2[i] * sc;
    }
}

// ---------------------------------------------------------------------------
// GEMM: C[M,N] = A[M,K] @ Bt[N,K]^T, 64x64 tile, 4 waves (wave = 16 rows).
// BN_SIDE: 0 = both bf16; 1 = A is f32 + bn1 fused; 2 = Bt is f32 + bn1 fused
// EPI 0: +bias[col] -> bf16 | 1: +bias+resid -> f32 AND bn2 -> bf16
//     2: gelu -> bf16      | 3: +resid -> f32 | 4: +bias[row] -> bf16
// ---------------------------------------------------------------------------
template <int EPI, int BN_SIDE>
__global__ __launch_bounds__(256) void gemm_bt(
        const void* __restrict__ Aptr, const void* __restrict__ Btptr,
        int M, int N, int K,
        const float* __restrict__ bnsc, const float* __restrict__ bnsh,
        const float* __restrict__ bias, const float* __restrict__ resid,
        float* __restrict__ out_f32, u16* __restrict__ out_bf,
        const float* __restrict__ b2sc, const float* __restrict__ b2sh) {
    __shared__ u16 lds_a[64][72];
    __shared__ u16 lds_b[64][72];
    const int t = threadIdx.x;
    const int wave = t >> 6, lane = t & 63;
    const int l = lane & 15, Q = lane >> 4;
    const int m0 = blockIdx.x * 64;
    const int n0 = blockIdx.y * 64;

    f32x4 acc[4];
#pragma unroll
    for (int nt = 0; nt < 4; ++nt) acc[nt] = (f32x4){0.f, 0.f, 0.f, 0.f};

    for (int k0 = 0; k0 < K; k0 += 64) {
        __syncthreads();
        // ---- stage A tile (64 rows x 64 k)
        if (BN_SIDE == 1) {
            const float* X = (const float*)Aptr;
            int row = t >> 2, seg = t & 3;
            const float* src = X + (size_t)(m0 + row) * K + k0 + seg * 16;
            u32 w[8];
#pragma unroll
            for (int j = 0; j < 4; ++j) {
                float4 xv = *(const float4*)(src + j * 4);
                float4 sc = *(const float4*)(bnsc + k0 + seg * 16 + j * 4);
                float4 sh = *(const float4*)(bnsh + k0 + seg * 16 + j * 4);
                float r0 = fmaf(xv.x, sc.x, sh.x), r1 = fmaf(xv.y, sc.y, sh.y);
                float r2 = fmaf(xv.z, sc.z, sh.z), r3 = fmaf(xv.w, sc.w, sh.w);
                w[2 * j]     = (u32)f2bf(r0) | ((u32)f2bf(r1) << 16);
                w[2 * j + 1] = (u32)f2bf(r2) | ((u32)f2bf(r3) << 16);
            }
            *(uint4*)(&lds_a[row][seg * 16])     = make_uint4(w[0], w[1], w[2], w[3]);
            *(uint4*)(&lds_a[row][seg * 16 + 8]) = make_uint4(w[4], w[5], w[6], w[7]);
        } else {
            const u16* A = (const u16*)Aptr;
#pragma unroll
            for (int i = 0; i < 2; ++i) {
                int c = t + i * 256;
                int row = c >> 3, c8 = c & 7;
                *(uint4*)(&lds_a[row][c8 * 8]) =
                    *(const uint4*)(A + (size_t)(m0 + row) * K + k0 + c8 * 8);
            }
        }
        // ---- stage B tile (64 rows x 64 k)
        if (BN_SIDE == 2) {
            const float* X = (const float*)Btptr;
            int row = t >> 2, seg = t & 3;
            const float* src = X + (size_t)(n0 + row) * K + k0 + seg * 16;
            u32 w[8];
#pragma unroll
            for (int j = 0; j < 4; ++j) {
                float4 xv = *(const float4*)(src + j * 4);
                float4 sc = *(const float4*)(bnsc + k0 + seg * 16 + j * 4);
                float4 sh = *(const float4*)(bnsh + k0 + seg * 16 + j * 4);
                float r0 = fmaf(xv.x, sc.x, sh.x), r1 = fmaf(xv.y, sc.y, sh.y);
                float r2 = fmaf(xv.z, sc.z, sh.z), r3 = fmaf(xv.w, sc.w, sh.w);
                w[2 * j]     = (u32)f2bf(r0) | ((u32)f2bf(r1) << 16);
                w[2 * j + 1] = (u32)f2bf(r2) | ((u32)f2bf(r3) << 16);
            }
            *(uint4*)(&lds_b[row][seg * 16])     = make_uint4(w[0], w[1], w[2], w[3]);
            *(uint4*)(&lds_b[row][seg * 16 + 8]) = make_uint4(w[4], w[5], w[6], w[7]);
        } else {
            const u16* Bt = (const u16*)Btptr;
#pragma unroll
            for (int i = 0; i < 2; ++i) {
                int c = t + i * 256;
                int row = c >> 3, c8 = c & 7;
                *(uint4*)(&lds_b[row][c8 * 8]) =
                    *(const uint4*)(Bt + (size_t)(n0 + row) * K + k0 + c8 * 8);
            }
        }
        __syncthreads();
#pragma unroll
        for (int kd = 0; kd < 2; ++kd) {
            short8 afr = *(const short8*)(&lds_a[wave * 16 + l][kd * 32 + Q * 8]);
            short8 bfr[4];
#pragma unroll
            for (int nt = 0; nt < 4; ++nt)
                bfr[nt] = *(const short8*)(&lds_b[nt * 16 + l][kd * 32 + Q * 8]);
#pragma unroll
            for (int nt = 0; nt < 4; ++nt)
                acc[nt] = __builtin_amdgcn_mfma_f32_16x16x32_bf16(afr, bfr[nt], acc[nt], 0, 0, 0);
        }
    }

#pragma unroll
    for (int nt = 0; nt < 4; ++nt)
#pragma unroll
        for (int r = 0; r < 4; ++r) {
            int row = m0 + wave * 16 + Q * 4 + r;
            int col = n0 + nt * 16 + l;
            float val = acc[nt][r];
            size_t oidx = (size_t)row * N + col;
            if (EPI == 0) {
                out_bf[oidx] = f2bf(val + bias[col]);
            } else if (EPI == 1) {
                val += bias[col] + resid[oidx];
                out_f32[oidx] = val;
                out_bf[oidx] = f2bf(fmaf(val, b2sc[col], b2sh[col]));
            } else if (EPI == 2) {
                float gl = 0.5f * val * (1.f + erff(val * 0.70710678118654752f));
                out_bf[oidx] = f2bf(gl);
            } else if (EPI == 3) {
                out_f32[oidx] = val + resid[oidx];
            } else {   // EPI 4: row bias (vT gemm)
                out_bf[oidx] = f2bf(val + bias[row]);
            }
        }
}

// ---------------------------------------------------------------------------
// Flash attention, S^T formulation. One wave = 16 q-rows; no LDS, no barriers.
// qk: [8192][512] bf16 (q cols 0..255 head-major, k cols 256..511)
// vT: [256][8192] bf16 (row = out-channel d (head-major), col = b*2048+s)
// ctx: [8192][256] bf16
// ---------------------------------------------------------------------------
__global__ __launch_bounds__(256) void attn_kernel(const u16* __restrict__ qk,
                                                   const u16* __restrict__ vT,
                                                   u16* __restrict__ ctx) {
    const int t = threadIdx.x;
    const int wave = t >> 6, lane = t & 63;
    const int l = lane & 15, Q = lane >> 4;
    const int qt = blockIdx.x;          // 0..31 (64 q rows / WG)
    const int bh = blockIdx.y;          // 0..15
    const int bb = bh >> 2, hd = bh & 3;
    const size_t rowbase = (size_t)bb * 2048;
    const int qbase = qt * 64 + wave * 16;

    // Q B-frags (held for whole loop): B[k=d][n=q], lane reads q-row l, d contig
    short8 qf[2];
    {
        const u16* qp = qk + (rowbase + qbase + l) * 512 + hd * 64 + Q * 8;
        qf[0] = *(const short8*)(qp);
        qf[1] = *(const short8*)(qp + 32);
    }

    f32x4 o[4];
#pragma unroll
    for (int dt = 0; dt < 4; ++dt) o[dt] = (f32x4){0.f, 0.f, 0.f, 0.f};
    float m_run = -1e30f, l_run = 0.f;
    const float C1 = 0.18033688011112042f;   // 0.125 * log2(e)

    const u16* kbase = qk + rowbase * 512 + 256 + hd * 64 + Q * 8;
    const u16* vbase = vT + (size_t)(hd * 64) * 8192 + rowbase + Q * 8;

    for (int kt = 0; kt < 32; ++kt) {
        // ---- S^T = K . Q^T   (4 s-tiles of 16, accumulated over d=64)
        short8 kf[4][2];
#pragma unroll
        for (int st = 0; st < 4; ++st) {
            const u16* kp = kbase + (size_t)(kt * 64 + st * 16 + l) * 512;
            kf[st][0] = *(const short8*)(kp);
            kf[st][1] = *(const short8*)(kp + 32);
        }
        f32x4 s[4];
#pragma unroll
        for (int st = 0; st < 4; ++st) s[st] = (f32x4){0.f, 0.f, 0.f, 0.f};
#pragma unroll
        for (int st = 0; st < 4; ++st)
#pragma unroll
            for (int kd = 0; kd < 2; ++kd)
                s[st] = __builtin_amdgcn_mfma_f32_16x16x32_bf16(kf[st][kd], qf[kd], s[st], 0, 0, 0);

        // ---- online softmax (per-lane state: q = l for every reg)
        float mx = -1e30f;
#pragma unroll
        for (int st = 0; st < 4; ++st)
#pragma unroll
            for (int r = 0; r < 4; ++r) mx = fmaxf(mx, s[st][r]);
        mx = fmaxf(mx, __shfl_xor(mx, 16));
        mx = fmaxf(mx, __shfl_xor(mx, 32));
        float mnew = fmaxf(m_run, mx);
        float alpha = exp2f((m_run - mnew) * C1);
        float nbase = -mnew * C1;
        float p[4][4];
        float rs = 0.f;
#pragma unroll
        for (int st = 0; st < 4; ++st)
#pragma unroll
            for (int r = 0; r < 4; ++r) {
                p[st][r] = exp2f(fmaf(s[st][r], C1, nbase));
                rs += p[st][r];
            }
        rs += __shfl_xor(rs, 16);
        rs += __shfl_xor(rs, 32);
        l_run = l_run * alpha + rs;
        m_run = mnew;
#pragma unroll
        for (int dt = 0; dt < 4; ++dt)
#pragma unroll
            for (int r = 0; r < 4; ++r) o[dt][r] *= alpha;

        // pack P^T to bf16 pairs: pp[st][dw] holds rows (2dw, 2dw+1)
        u32 pp[4][2];
#pragma unroll
        for (int st = 0; st < 4; ++st) {
            pp[st][0] = pack_bf2(p[st][0], p[st][1]);
            pp[st][1] = pack_bf2(p[st][2], p[st][3]);
        }

        // ---- O^T += V^T . P^T  (2 chunks of K=32)
#pragma unroll
        for (int c = 0; c < 2; ++c) {
            // B-frag dword d = pp[2c + (Q>>1)][d&1] from lane quad 2(Q&1)+(d>>1)
            union { u32 u[4]; short8 s8; } pf;
#pragma unroll
            for (int d = 0; d < 4; ++d) {
                int srcLane = (2 * (Q & 1) + (d >> 1)) * 16 + l;
                u32 va = __shfl((int)pp[2 * c][d & 1], srcLane);
                u32 vb = __shfl((int)pp[2 * c + 1][d & 1], srcLane);
                pf.u[d] = (Q >> 1) ? vb : va;
            }
#pragma unroll
            for (int dt = 0; dt < 4; ++dt) {
                const u16* vp = vbase + (size_t)(dt * 16 + l) * 8192 + kt * 64 + c * 32;
                short8 vf = *(const short8*)vp;
                o[dt] = __builtin_amdgcn_mfma_f32_16x16x32_bf16(vf, pf.s8, o[dt], 0, 0, 0);
            }
        }
    }

    // ---- epilogue: ctx[q][d] = O^T[d][q] / l
    float inv = 1.0f / l_run;
#pragma unroll
    for (int dt = 0; dt < 4; ++dt) {
        ushort4 pk;
        pk.x = f2bf(o[dt][0] * inv);
        pk.y = f2bf(o[dt][1] * inv);
        pk.z = f2bf(o[dt][2] * inv);
        pk.w = f2bf(o[dt][3] * inv);
        *(ushort4*)(ctx + (rowbase + qbase + l) * 256 + hd * 64 + dt * 16 + Q * 4) = pk;
    }
}

// ---------------------------------------------------------------------------
extern "C" void kernel_launch(void* const* d_in, const int* in_sizes, int n_in,
                              void* d_out, int out_size, void* d_ws, size_t ws_size,
                              hipStream_t stream) {
    (void)in_sizes; (void)n_in; (void)out_size; (void)ws_size;
    const float* x  = (const float*)d_in[0];
    const float* g1 = (const float*)d_in[1];
    const float* b1 = (const float*)d_in[2];
    const float* m1 = (const float*)d_in[3];
    const float* v1 = (const float*)d_in[4];
    const float* wq = (const float*)d_in[5];
    const float* bq = (const float*)d_in[6];
    const float* wk = (const float*)d_in[7];
    const float* bk = (const float*)d_in[8];
    const float* wv = (const float*)d_in[9];
    const float* bv = (const float*)d_in[10];
    const float* wo = (const float*)d_in[11];
    const float* bo = (const float*)d_in[12];
    const float* g2 = (const float*)d_in[13];
    const float* b2 = (const float*)d_in[14];
    const float* m2 = (const float*)d_in[15];
    const float* v2 = (const float*)d_in[16];
    const float* w1 = (const float*)d_in[17];
    const float* w2 = (const float*)d_in[18];

    char* ws = (char*)d_ws;
    u16*   qkb   = (u16*)(ws + 0);            // [8192][512] bf16
    u16*   vTb   = (u16*)(ws + 8388608);      // [256][8192] bf16
    u16*   ctx   = (u16*)(ws + 12582912);     // [8192][256] bf16
    float* x1    = (float*)(ws + 16777216);   // [8192][256] f32
    u16*   h2    = (u16*)(ws + 25165824);     // [8192][256] bf16
    u16*   gbuf  = (u16*)(ws + 29360128);     // [8192][1024] bf16
    u16*   wqkT  = (u16*)(ws + 46137344);     // [512][256]
    u16*   wvT   = (u16*)(ws + 46399488);     // [256][256]
    u16*   woT   = (u16*)(ws + 46530560);     // [256][256]
    u16*   w1T   = (u16*)(ws + 46661632);     // [1024][256]
    u16*   w2T   = (u16*)(ws + 47185920);     // [256][1024]
    float* bqk   = (float*)(ws + 47710208);   // [512]
    float* bn1sc = (float*)(ws + 47712256);   // [256]
    float* bn1sh = (float*)(ws + 47713280);
    float* bn2sc = (float*)(ws + 47714304);
    float* bn2sh = (float*)(ws + 47715328);
    float* out   = (float*)d_out;

    prep_kernel<<<3076, 256, 0, stream>>>(wq, wk, wv, wo, w1, w2, bq, bk,
                                          g1, b1, m1, v1, g2, b2, m2, v2,
                                          wqkT, wvT, woT, w1T, w2T, bqk,
                                          bn1sc, bn1sh, bn2sc, bn2sh);
    // QK projection: A = bn1(x) fused, Bt = wqkT
    gemm_bt<0, 1><<<dim3(128, 8), 256, 0, stream>>>(
        x, wqkT, 8192, 512, 256, bn1sc, bn1sh, bqk, nullptr, nullptr, qkb, nullptr, nullptr);
    // V^T projection: A = wvT, Bt = bn1(x) fused  -> vT [256][8192], row bias bv
    gemm_bt<4, 2><<<dim3(4, 128), 256, 0, stream>>>(
        wvT, x, 256, 8192, 256, bn1sc, bn1sh, bv, nullptr, nullptr, vTb, nullptr, nullptr);
    // attention
    attn_kernel<<<dim3(32, 16), 256, 0, stream>>>(qkb, vTb, ctx);
    // O projection + residual + bn2
    gemm_bt<1, 0><<<dim3(128, 4), 256, 0, stream>>>(
        ctx, woT, 8192, 256, 256, nullptr, nullptr, bo, x, x1, h2, bn2sc, bn2sh);
    // FFN1 + gelu
    gemm_bt<2, 0><<<dim3(128, 16), 256, 0, stream>>>(
        h2, w1T, 8192, 1024, 256, nullptr, nullptr, nullptr, nullptr, nullptr, gbuf, nullptr, nullptr);
    // FFN2 + residual -> out
    gemm_bt<3, 0><<<dim3(128, 4), 256, 0, stream>>>(
        gbuf, w2T, 8192, 256, 1024, nullptr, nullptr, nullptr, x1, out, nullptr, nullptr, nullptr);
}

// Round 3
// 211.092 us; speedup vs baseline: 1.4875x; 1.3686x over previous
//
#include <hip/hip_runtime.h>

typedef unsigned short u16;
typedef unsigned int u32;
typedef short short8 __attribute__((ext_vector_type(8)));
typedef float f32x4 __attribute__((ext_vector_type(4)));

#define EPS 1e-3f
#define C1F 0.18033688011112042f   // 0.125 * log2(e), folded into wk/bk in prep

static __device__ __forceinline__ u16 f2bf(float f) {
    u32 u = __float_as_uint(f);
    u += 0x7fffu + ((u >> 16) & 1u);   // round-to-nearest-even
    return (u16)(u >> 16);
}
// pack two floats to bf16 pair: low half = a, high half = b
static __device__ __forceinline__ u32 pack_bf2(float a, float b) {
    u32 ua = __float_as_uint(a) + 0x8000u;
    u32 ub = __float_as_uint(b) + 0x8000u;
    return __builtin_amdgcn_perm(ub, ua, 0x07060302u);
}
// async global->LDS 16B per lane (lds dest must be wave-uniform base)
static __device__ __forceinline__ void async_cp16(const void* g, void* l) {
    __builtin_amdgcn_global_load_lds(
        (const __attribute__((address_space(1))) unsigned int*)g,
        (__attribute__((address_space(3))) unsigned int*)l, 16, 0, 0);
}

// ---------------------------------------------------------------------------
// prep: weights -> bf16 [N][K]; qk-concat (k side pre-scaled by C1); bn sc/sh
// ---------------------------------------------------------------------------
__global__ void prep_kernel(const float* __restrict__ wq, const float* __restrict__ wk,
                            const float* __restrict__ wv, const float* __restrict__ wo,
                            const float* __restrict__ w1, const float* __restrict__ w2,
                            const float* __restrict__ bq, const float* __restrict__ bk,
                            const float* __restrict__ g1, const float* __restrict__ b1,
                            const float* __restrict__ m1, const float* __restrict__ v1,
                            const float* __restrict__ g2, const float* __restrict__ b2,
                            const float* __restrict__ m2, const float* __restrict__ v2,
                            u16* __restrict__ wqkT, u16* __restrict__ wvT,
                            u16* __restrict__ woT, u16* __restrict__ w1T,
                            u16* __restrict__ w2T, float* __restrict__ bqk,
                            float* __restrict__ bn1sc, float* __restrict__ bn1sh,
                            float* __restrict__ bn2sc, float* __restrict__ bn2sh) {
    int idx = blockIdx.x * 256 + threadIdx.x;
    if (idx < 131072) {                       // wqkT [512][256]
        int n = idx >> 8, k = idx & 255;
        float v = (n < 256) ? wq[k * 256 + n] : wk[k * 256 + (n - 256)] * C1F;
        wqkT[idx] = f2bf(v);
    } else if (idx < 196608) {                // wvT [256][256]
        int i = idx - 131072; int n = i >> 8, k = i & 255;
        wvT[i] = f2bf(wv[k * 256 + n]);
    } else if (idx < 262144) {                // woT [256][256]
        int i = idx - 196608; int n = i >> 8, k = i & 255;
        woT[i] = f2bf(wo[k * 256 + n]);
    } else if (idx < 524288) {                // w1T [1024][256]
        int i = idx - 262144; int n = i >> 8, k = i & 255;
        w1T[i] = f2bf(w1[k * 1024 + n]);
    } else if (idx < 786432) {                // w2T [256][1024]
        int i = idx - 524288; int n = i >> 10, k = i & 1023;
        w2T[i] = f2bf(w2[k * 256 + n]);
    } else if (idx < 786944) {                // bqk [512]
        int i = idx - 786432;
        bqk[i] = (i < 256) ? bq[i] : bk[i - 256] * C1F;
    } else if (idx < 787200) {                // bn1 sc/sh
        int i = idx - 786944;
        float sc = g1[i] * rsqrtf(v1[i] + EPS);
        bn1sc[i] = sc; bn1sh[i] = b1[i] - m1[i] * sc;
    } else if (idx < 787456) {                // bn2 sc/sh
        int i = idx - 787200;
        float sc = g2[i] * rsqrtf(v2[i] + EPS);
        bn2sc[i] = sc; bn2sh[i] = b2[i] - m2[i] * sc;
    }
}

// ---------------------------------------------------------------------------
// bn1: h = bn1(x) -> bf16 [8192][256]
// ---------------------------------------------------------------------------
__global__ void bn1_kernel(const float* __restrict__ x, const float* __restrict__ sc,
                           const float* __restrict__ sh, u16* __restrict__ h) {
    int idx = blockIdx.x * 256 + threadIdx.x;
    int base = idx * 4;
    int c = base & 255;
    float4 xv = *(const float4*)(x + base);
    float4 s4 = *(const float4*)(sc + c);
    float4 h4 = *(const float4*)(sh + c);
    ushort4 pk;
    pk.x = f2bf(fmaf(xv.x, s4.x, h4.x));
    pk.y = f2bf(fmaf(xv.y, s4.y, h4.y));
    pk.z = f2bf(fmaf(xv.z, s4.z, h4.z));
    pk.w = f2bf(fmaf(xv.w, s4.w, h4.w));
    *(ushort4*)(h + base) = pk;
}

// ---------------------------------------------------------------------------
// Weight-stationary GEMM: C[M,N] = A[M,K] @ Bt[N,K]^T.
// WG = 4 waves; wave = MT*16 m-rows x 64 n-cols. B tile staged to LDS once per
// 256-k chunk (XOR-swizzled 16B chunks, global_load_lds); A frags from global.
// EPI 0: +bias[col]->bf16 | 1: +bias+resid->f32 AND bn2->bf16
//     2: gelu->bf16       | 3: +resid->f32
// ---------------------------------------------------------------------------
template <int EPI, int MT>
__global__ __launch_bounds__(256) void gemm_ws(
        const u16* __restrict__ A, const u16* __restrict__ Bt,
        int M, int N, int K,
        const float* __restrict__ bias, const float* __restrict__ resid,
        float* __restrict__ out_f32, u16* __restrict__ out_bf,
        const float* __restrict__ b2sc, const float* __restrict__ b2sh) {
    __shared__ u16 lds_b[64 * 256];            // 32 KB per 256-k chunk
    const int t = threadIdx.x;
    const int w = t >> 6, lane = t & 63;
    const int l = lane & 15, Q = lane >> 4;
    const int m0 = blockIdx.x * (MT * 64);
    const int n0 = blockIdx.y * 64;

    f32x4 acc[MT][4];
#pragma unroll
    for (int mt = 0; mt < MT; ++mt)
#pragma unroll
        for (int nt = 0; nt < 4; ++nt) acc[mt][nt] = (f32x4){0.f, 0.f, 0.f, 0.f};

    for (int kc = 0; kc < K; kc += 256) {
        __syncthreads();
        // stage Bt[n0..+64][kc..+256]: 2048 16B chunks, swizzled slot = c ^ (r&7) on low 3 bits
#pragma unroll
        for (int j = 0; j < 8; ++j) {
            int cw = (w * 8 + j) * 64 + lane;
            int r = cw >> 5;
            int cs = cw & 31;
            int c = (cs & 24) | ((cs & 7) ^ (r & 7));
            async_cp16(Bt + (size_t)(n0 + r) * K + kc + c * 8, (char*)lds_b + (w * 8 + j) * 1024);
        }
        __syncthreads();   // vmcnt drain -> tile ready
#pragma unroll
        for (int kd = 0; kd < 8; ++kd) {
            short8 bfr[4];
#pragma unroll
            for (int nt = 0; nt < 4; ++nt) {
                int r = nt * 16 + l;
                int c = kd * 4 + Q;
                int slot = (c & 24) | ((c & 7) ^ (r & 7));
                bfr[nt] = *(const short8*)(lds_b + r * 256 + slot * 8);
            }
#pragma unroll
            for (int mt = 0; mt < MT; ++mt) {
                short8 afr = *(const short8*)(A + (size_t)(m0 + w * 16 * MT + mt * 16 + l) * K
                                              + kc + kd * 32 + Q * 8);
#pragma unroll
                for (int nt = 0; nt < 4; ++nt)
                    acc[mt][nt] = __builtin_amdgcn_mfma_f32_16x16x32_bf16(afr, bfr[nt], acc[mt][nt], 0, 0, 0);
            }
        }
    }

#pragma unroll
    for (int mt = 0; mt < MT; ++mt)
#pragma unroll
        for (int nt = 0; nt < 4; ++nt)
#pragma unroll
            for (int r = 0; r < 4; ++r) {
                int row = m0 + w * 16 * MT + mt * 16 + Q * 4 + r;
                int col = n0 + nt * 16 + l;
                float val = acc[mt][nt][r];
                size_t oidx = (size_t)row * N + col;
                if (EPI == 0) {
                    out_bf[oidx] = f2bf(val + bias[col]);
                } else if (EPI == 1) {
                    val += bias[col] + resid[oidx];
                    out_f32[oidx] = val;
                    out_bf[oidx] = f2bf(fmaf(val, b2sc[col], b2sh[col]));
                } else if (EPI == 2) {
                    float gl = 0.5f * val * (1.f + erff(val * 0.70710678118654752f));
                    out_bf[oidx] = f2bf(gl);
                } else {
                    out_f32[oidx] = val + resid[oidx];
                }
            }
}

// ---------------------------------------------------------------------------
// Old barrier GEMM, kept only for the V^T projection (A = wvT weights).
// EPI 4: +bias[row] -> bf16
// ---------------------------------------------------------------------------
__global__ __launch_bounds__(256) void gemm_bt4(
        const u16* __restrict__ A, const u16* __restrict__ Bt,
        int M, int N, int K,
        const float* __restrict__ bias, u16* __restrict__ out_bf) {
    __shared__ u16 lds_a[64][72];
    __shared__ u16 lds_b[64][72];
    const int t = threadIdx.x;
    const int wave = t >> 6, lane = t & 63;
    const int l = lane & 15, Q = lane >> 4;
    const int m0 = blockIdx.x * 64;
    const int n0 = blockIdx.y * 64;

    f32x4 acc[4];
#pragma unroll
    for (int nt = 0; nt < 4; ++nt) acc[nt] = (f32x4){0.f, 0.f, 0.f, 0.f};

    for (int k0 = 0; k0 < K; k0 += 64) {
        __syncthreads();
#pragma unroll
        for (int i = 0; i < 2; ++i) {
            int c = t + i * 256;
            int row = c >> 3, c8 = c & 7;
            *(uint4*)(&lds_a[row][c8 * 8]) =
                *(const uint4*)(A + (size_t)(m0 + row) * K + k0 + c8 * 8);
            *(uint4*)(&lds_b[row][c8 * 8]) =
                *(const uint4*)(Bt + (size_t)(n0 + row) * K + k0 + c8 * 8);
        }
        __syncthreads();
#pragma unroll
        for (int kd = 0; kd < 2; ++kd) {
            short8 afr = *(const short8*)(&lds_a[wave * 16 + l][kd * 32 + Q * 8]);
            short8 bfr[4];
#pragma unroll
            for (int nt = 0; nt < 4; ++nt)
                bfr[nt] = *(const short8*)(&lds_b[nt * 16 + l][kd * 32 + Q * 8]);
#pragma unroll
            for (int nt = 0; nt < 4; ++nt)
                acc[nt] = __builtin_amdgcn_mfma_f32_16x16x32_bf16(afr, bfr[nt], acc[nt], 0, 0, 0);
        }
    }
#pragma unroll
    for (int nt = 0; nt < 4; ++nt)
#pragma unroll
        for (int r = 0; r < 4; ++r) {
            int row = m0 + wave * 16 + Q * 4 + r;
            int col = n0 + nt * 16 + l;
            out_bf[(size_t)row * N + col] = f2bf(acc[nt][r] + bias[row]);
        }
}

// ---------------------------------------------------------------------------
// Flash attention v3: S^T form, no-max softmax (K pre-scaled by C1, clamp 100),
// K/V tiles double-buffered in LDS via global_load_lds, P^T via per-wave LDS.
// Wave = 32 q-rows; WG = 128 q; grid (16 qtiles, 16 bh, 2 s-splits).
// Writes fp32 partials opart[sp][bh][2048][64], lpart[sp][bh][2048].
// ---------------------------------------------------------------------------
static __device__ __forceinline__ void stage_tiles(const u16* kglob, const u16* vglob,
                                                   u16* kdst, u16* vdst,
                                                   int w, int lane, int kt) {
#pragma unroll
    for (int j = 0; j < 2; ++j) {
        int cw = (w * 2 + j) * 64 + lane;     // chunk position 0..511
        int r = cw >> 3;                       // tile row 0..63
        int c = (cw & 7) ^ (r & 7);            // swizzled source chunk
        async_cp16(kglob + ((size_t)(kt * 64 + r)) * 512 + c * 8, kdst + (w * 2 + j) * 512);
        async_cp16(vglob + ((size_t)r) * 8192 + kt * 64 + c * 8, vdst + (w * 2 + j) * 512);
    }
}

__global__ __launch_bounds__(256) void attn_kernel(const u16* __restrict__ qk,
                                                   const u16* __restrict__ vT,
                                                   float* __restrict__ opart,
                                                   float* __restrict__ lpart) {
    __shared__ u16 kbuf[2][4096];     // 64x64 bf16, swizzled
    __shared__ u16 vbuf[2][4096];
    __shared__ u32 pbuf[8 * 16 * 36]; // per (wave,qg): 16 rows x 36 dwords
    const int t = threadIdx.x;
    const int w = t >> 6, lane = t & 63;
    const int l = lane & 15, Q = lane >> 4;
    const int qt = blockIdx.x;        // 0..15
    const int bh = blockIdx.y;        // 0..15
    const int sp = blockIdx.z;        // 0..1
    const int bb = bh >> 2, hd = bh & 3;
    const size_t rowbase = (size_t)bb * 2048;
    const int q0 = qt * 128 + w * 32;            // wave q base (local)
    const int s_base = sp * 1024;

    // Q B-frags, held for the whole loop
    short8 qf[2][2];
#pragma unroll
    for (int qg = 0; qg < 2; ++qg)
#pragma unroll
        for (int kd = 0; kd < 2; ++kd)
            qf[qg][kd] = *(const short8*)(qk + (rowbase + q0 + qg * 16 + l) * 512
                                          + hd * 64 + kd * 32 + Q * 8);

    f32x4 o[2][4];
#pragma unroll
    for (int qg = 0; qg < 2; ++qg)
#pragma unroll
        for (int dt = 0; dt < 4; ++dt) o[qg][dt] = (f32x4){0.f, 0.f, 0.f, 0.f};
    float lacc[2] = {0.f, 0.f};

    const u16* kglob = qk + (rowbase + s_base) * 512 + 256 + hd * 64;   // row stride 512
    const u16* vglob = vT + ((size_t)(hd * 64)) * 8192 + rowbase + s_base; // row stride 8192
    u32* pw = pbuf + w * 1152;        // wave's 2 q-group regions (2*16*36)

    stage_tiles(kglob, vglob, kbuf[0], vbuf[0], w, lane, 0);

    for (int kt = 0; kt < 16; ++kt) {
        __syncthreads();              // drains vmcnt: tile kt ready
        if (kt < 15)
            stage_tiles(kglob, vglob, kbuf[(kt + 1) & 1], vbuf[(kt + 1) & 1], w, lane, kt + 1);
        const u16* kb = kbuf[kt & 1];
        const u16* vb = vbuf[kt & 1];

        // S^T = K.Q^T -> exp2 -> pack -> store P^T (per-wave LDS region)
#pragma unroll
        for (int st = 0; st < 4; ++st) {
            int r = st * 16 + l;
            short8 kf0 = *(const short8*)(kb + r * 64 + ((0 + Q) ^ (r & 7)) * 8);
            short8 kf1 = *(const short8*)(kb + r * 64 + ((4 + Q) ^ (r & 7)) * 8);
#pragma unroll
            for (int qg = 0; qg < 2; ++qg) {
                f32x4 s = (f32x4){0.f, 0.f, 0.f, 0.f};
                s = __builtin_amdgcn_mfma_f32_16x16x32_bf16(kf0, qf[qg][0], s, 0, 0, 0);
                s = __builtin_amdgcn_mfma_f32_16x16x32_bf16(kf1, qf[qg][1], s, 0, 0, 0);
                float p0 = exp2f(fminf(s[0], 100.f));
                float p1 = exp2f(fminf(s[1], 100.f));
                float p2 = exp2f(fminf(s[2], 100.f));
                float p3 = exp2f(fminf(s[3], 100.f));
                lacc[qg] += (p0 + p1) + (p2 + p3);
                u32 d0 = pack_bf2(p0, p1);
                u32 d1 = pack_bf2(p2, p3);
                *(uint2*)&pw[qg * 576 + l * 36 + st * 8 + Q * 2] = make_uint2(d0, d1);
            }
        }

        // O^T += V^T . P^T  (2 k-chunks of 32 s)
#pragma unroll
        for (int cc = 0; cc < 2; ++cc) {
            short8 pf0 = *(const short8*)&pw[l * 36 + cc * 16 + Q * 4];
            short8 pf1 = *(const short8*)&pw[576 + l * 36 + cc * 16 + Q * 4];
#pragma unroll
            for (int dt = 0; dt < 4; ++dt) {
                int r = dt * 16 + l;
                short8 vf = *(const short8*)(vb + r * 64 + ((cc * 4 + Q) ^ (r & 7)) * 8);
                o[0][dt] = __builtin_amdgcn_mfma_f32_16x16x32_bf16(vf, pf0, o[0][dt], 0, 0, 0);
                o[1][dt] = __builtin_amdgcn_mfma_f32_16x16x32_bf16(vf, pf1, o[1][dt], 0, 0, 0);
            }
        }
    }

    // epilogue: reduce l over Q-groups; write fp32 partials
#pragma unroll
    for (int qg = 0; qg < 2; ++qg) {
        float v = lacc[qg];
        v += __shfl_xor(v, 16);
        v += __shfl_xor(v, 32);
        lacc[qg] = v;
    }
    float* ob = opart + (((size_t)sp * 16 + bh) * 2048 + q0) * 64;
#pragma unroll
    for (int qg = 0; qg < 2; ++qg)
#pragma unroll
        for (int dt = 0; dt < 4; ++dt)
            *(f32x4*)(ob + (size_t)(qg * 16 + l) * 64 + dt * 16 + Q * 4) = o[qg][dt];
    if (Q == 0) {
        size_t lb = ((size_t)sp * 16 + bh) * 2048 + q0;
        lpart[lb + l] = lacc[0];
        lpart[lb + 16 + l] = lacc[1];
    }
}

// ---------------------------------------------------------------------------
// combine: ctx[b*2048+s][h*64+d] = (o1+o2)/(l1+l2)  -> bf16
// ---------------------------------------------------------------------------
__global__ void combine_kernel(const float* __restrict__ opart,
                               const float* __restrict__ lpart,
                               u16* __restrict__ ctx) {
    int idx = blockIdx.x * 256 + threadIdx.x;   // 524288 threads x 4 elems
    int e = idx * 4;
    int row = e >> 8, col = e & 255;
    int b = row >> 11, s = row & 2047, h = col >> 6, d = col & 63;
    size_t pb = (((size_t)(b * 4 + h)) * 2048 + s) * 64 + d;
    f32x4 o1 = *(const f32x4*)(opart + pb);
    f32x4 o2 = *(const f32x4*)(opart + 2097152 + pb);
    size_t lb = (size_t)(b * 4 + h) * 2048 + s;
    float li = 1.0f / (lpart[lb] + lpart[32768 + lb]);
    ushort4 pk;
    pk.x = f2bf((o1[0] + o2[0]) * li);
    pk.y = f2bf((o1[1] + o2[1]) * li);
    pk.z = f2bf((o1[2] + o2[2]) * li);
    pk.w = f2bf((o1[3] + o2[3]) * li);
    *(ushort4*)(ctx + e) = pk;
}

// ---------------------------------------------------------------------------
extern "C" void kernel_launch(void* const* d_in, const int* in_sizes, int n_in,
                              void* d_out, int out_size, void* d_ws, size_t ws_size,
                              hipStream_t stream) {
    (void)in_sizes; (void)n_in; (void)out_size; (void)ws_size;
    const float* x  = (const float*)d_in[0];
    const float* g1 = (const float*)d_in[1];
    const float* b1 = (const float*)d_in[2];
    const float* m1 = (const float*)d_in[3];
    const float* v1 = (const float*)d_in[4];
    const float* wq = (const float*)d_in[5];
    const float* bq = (const float*)d_in[6];
    const float* wk = (const float*)d_in[7];
    const float* bk = (const float*)d_in[8];
    const float* wv = (const float*)d_in[9];
    const float* bv = (const float*)d_in[10];
    const float* wo = (const float*)d_in[11];
    const float* bo = (const float*)d_in[12];
    const float* g2 = (const float*)d_in[13];
    const float* b2 = (const float*)d_in[14];
    const float* m2 = (const float*)d_in[15];
    const float* v2 = (const float*)d_in[16];
    const float* w1 = (const float*)d_in[17];
    const float* w2 = (const float*)d_in[18];

    char* ws = (char*)d_ws;
    u16*   qkb   = (u16*)(ws + 0);            // [8192][512] bf16
    u16*   ctxh  = (u16*)(ws + 8388608);      // h (bn1 out) THEN ctx (combine out) [8192][256]
    float* x1    = (float*)(ws + 12582912);   // [8192][256] f32 ; first 256KB doubles as lpart
    u16*   h2    = (u16*)(ws + 20971520);     // [8192][256] bf16
    float* opart = (float*)(ws + 25165824);   // 16 MB attn partials; later gbuf overlays
    u16*   gbuf  = (u16*)(ws + 25165824);     // [8192][1024] bf16
    u16*   vTb   = (u16*)(ws + 41943040);     // [256][8192] bf16
    u16*   wqkT  = (u16*)(ws + 46137344);     // [512][256]
    u16*   wvT   = (u16*)(ws + 46399488);     // [256][256]
    u16*   woT   = (u16*)(ws + 46530560);     // [256][256]
    u16*   w1T   = (u16*)(ws + 46661632);     // [1024][256]
    u16*   w2T   = (u16*)(ws + 47185920);     // [256][1024]
    float* bqk   = (float*)(ws + 47710208);   // [512]
    float* bn1sc = (float*)(ws + 47712256);
    float* bn1sh = (float*)(ws + 47713280);
    float* bn2sc = (float*)(ws + 47714304);
    float* bn2sh = (float*)(ws + 47715328);
    float* lpart = (float*)(ws + 12582912);   // overlays x1 (dead until O-proj)
    u16*   h_buf = ctxh;
    u16*   ctx   = ctxh;
    float* out   = (float*)d_out;

    prep_kernel<<<3076, 256, 0, stream>>>(wq, wk, wv, wo, w1, w2, bq, bk,
                                          g1, b1, m1, v1, g2, b2, m2, v2,
                                          wqkT, wvT, woT, w1T, w2T, bqk,
                                          bn1sc, bn1sh, bn2sc, bn2sh);
    bn1_kernel<<<2048, 256, 0, stream>>>(x, bn1sc, bn1sh, h_buf);
    // QK projection (k-side pre-scaled by C1): qkb[8192][512]
    gemm_ws<0, 2><<<dim3(64, 8), 256, 0, stream>>>(
        h_buf, wqkT, 8192, 512, 256, bqk, nullptr, nullptr, qkb, nullptr, nullptr);
    // V^T projection: vTb[256][8192], row bias bv
    gemm_bt4<<<dim3(4, 128), 256, 0, stream>>>(wvT, h_buf, 256, 8192, 256, bv, vTb);
    // attention partials + combine
    attn_kernel<<<dim3(16, 16, 2), 256, 0, stream>>>(qkb, vTb, opart, lpart);
    combine_kernel<<<2048, 256, 0, stream>>>(opart, lpart, ctx);
    // O projection + residual + bn2
    gemm_ws<1, 1><<<dim3(128, 4), 256, 0, stream>>>(
        ctx, woT, 8192, 256, 256, bo, x, x1, h2, bn2sc, bn2sh);
    // FFN1 + gelu
    gemm_ws<2, 2><<<dim3(64, 16), 256, 0, stream>>>(
        h2, w1T, 8192, 1024, 256, nullptr, nullptr, nullptr, gbuf, nullptr, nullptr);
    // FFN2 + residual -> out
    gemm_ws<3, 1><<<dim3(128, 4), 256, 0, stream>>>(
        gbuf, w2T, 8192, 256, 1024, nullptr, x1, out, nullptr, nullptr, nullptr);
}